// Round 17
// baseline (371.784 us; speedup 1.0000x reference)
//
#include <hip/hip_runtime.h>
#include <hip/hip_bf16.h>

// Problem constants (from reference): N=100000, F_IN=HID=256, E=800000, G=256
#define HID 256
#define NGRAPH 256

typedef __bf16 bf16_t;
typedef __attribute__((ext_vector_type(8))) __bf16 bf16x8;
typedef __attribute__((ext_vector_type(4))) __bf16 bf16x4;
typedef __attribute__((ext_vector_type(4))) float f32x4;

// ---------------------------------------------------------------------------
// prep: zero degi (blocks [0,ZB)) + W1/W2 -> fragment-major bf16 (rest).
//   Wf[((k0*16 + nt)*64 + kg*16 + m)*8 + j] = bf16( W[k0*32+kg*8+j][nt*16+m] )
// ---------------------------------------------------------------------------
__global__ __launch_bounds__(256) void prep_kernel(
    int* __restrict__ degi, int N, int ZB,
    const float* __restrict__ W1, bf16_t* __restrict__ Wf1,
    const float* __restrict__ W2, bf16_t* __restrict__ Wf2) {
    int b = blockIdx.x;
    if (b < ZB) {
        int i = b * 256 + threadIdx.x;
        if (i < N) degi[i] = 0;
        return;
    }
    int gi = (b - ZB) * 256 + threadIdx.x;  // 0..131071
    const float* W = (gi < 65536) ? W1 : W2;
    bf16_t* Wf = (gi < 65536) ? Wf1 : Wf2;
    int idx = gi & 65535;
    float w = W[idx];
    int k = idx >> 8, n = idx & 255;
    int k0 = k >> 5, kg = (k >> 3) & 3, j = k & 7;
    int nt = n >> 4, m = n & 15;
    Wf[(size_t)(((k0 * 16 + nt) * 64) + kg * 16 + m) * 8 + j] = (bf16_t)w;
}

// ---------------------------------------------------------------------------
// count_deg (blocks [0,CB)) + graph_bounds (rest; batch sorted).
// ---------------------------------------------------------------------------
__global__ void count_bounds_kernel(const int* __restrict__ ei, int E, int CB,
                                    int* __restrict__ deg,
                                    const int* __restrict__ batch, int N, int G,
                                    int* __restrict__ gstart) {
    int b = blockIdx.x;
    if (b < CB) {
        int e = b * 256 + threadIdx.x;
        if (e < E) atomicAdd(&deg[ei[E + e]], 1);
        return;
    }
    int i = (b - CB) * 256 + threadIdx.x;
    if (i > N) return;
    int cur = (i < N) ? batch[i] : G;
    int prev = (i == 0) ? -1 : batch[i - 1];
    for (int g = prev + 1; g <= cur; ++g) gstart[g] = i;
}

#define SCHUNK 512

__global__ __launch_bounds__(256) void scan_pass1_kernel(
    const int* __restrict__ deg, int N, int* __restrict__ bsum) {
    __shared__ int red[256];
    int b = blockIdx.x, t = threadIdx.x;
    int i0 = b * SCHUNK + 2 * t;
    int v = 0;
    if (i0 < N) v += deg[i0];
    if (i0 + 1 < N) v += deg[i0 + 1];
    red[t] = v;
    __syncthreads();
    for (int s = 128; s > 0; s >>= 1) {
        if (t < s) red[t] += red[t + s];
        __syncthreads();
    }
    if (t == 0) bsum[b] = red[0];
}

__global__ __launch_bounds__(256) void scan_pass2_kernel(
    const int* __restrict__ bsum, int NB, int* __restrict__ boff) {
    __shared__ int s[256];
    int t = threadIdx.x;
    int v = (t < NB) ? bsum[t] : 0;
    s[t] = v;
    __syncthreads();
    for (int off = 1; off < 256; off <<= 1) {
        int x = s[t];
        if (t >= off) x += s[t - off];
        __syncthreads();
        s[t] = x;
        __syncthreads();
    }
    if (t < NB) boff[t] = s[t] - v;  // exclusive
}

__global__ __launch_bounds__(256) void scan_pass3_kernel(
    const int* __restrict__ deg, int N, const int* __restrict__ boff,
    int* __restrict__ rowptr, int* __restrict__ cursor, float* __restrict__ invd) {
    __shared__ int s[256];
    int b = blockIdx.x, t = threadIdx.x;
    int i0 = b * SCHUNK + 2 * t;
    int d0 = (i0 < N) ? deg[i0] : 0;
    int d1 = (i0 + 1 < N) ? deg[i0 + 1] : 0;
    int pair = d0 + d1;
    s[t] = pair;
    __syncthreads();
    for (int off = 1; off < 256; off <<= 1) {
        int x = s[t];
        if (t >= off) x += s[t - off];
        __syncthreads();
        s[t] = x;
        __syncthreads();
    }
    int excl = s[t] - pair + boff[b];
    if (i0 < N) {
        rowptr[i0] = excl;
        cursor[i0] = excl;
        invd[i0] = rsqrtf((float)d0 + 1.0f);
    }
    if (i0 + 1 < N) {
        int e1 = excl + d0;
        rowptr[i0 + 1] = e1;
        cursor[i0 + 1] = e1;
        invd[i0 + 1] = rsqrtf((float)d1 + 1.0f);
    }
}

// ---------------------------------------------------------------------------
// MFMA GEMM + optional fused fill_csr (blocks [0,FB) do the CSR scatter so it
// overlaps gemm1's compute — they're independent: gemm needs invd, fill needs
// cursor, both ready). GEMM: hs[i,:] = bf16( (X[i,:] @ W) * rowscale[i] ),
// single product (layer-1 x quantized to bf16 in-register). GBM=128, 512
// threads, B staged in LDS in two 64KB half-K chunks. Round-17: staging via
// __builtin_amdgcn_global_load_lds width=16 (async direct-to-LDS, no VGPR
// round-trip — guide m93->m97 lever; LDS dest is wave-uniform base + lane*16,
// our linear layout matches exactly). A-loads pre-issued per chunk.
// MFMA layout facts (verified m89/m91): D col=lane&15, row=(lane>>4)*4+reg.
// ---------------------------------------------------------------------------
#define GBM 128

template <int INFP32>
__global__ __launch_bounds__(512, 4) void gemm_fill_kernel(
    const void* __restrict__ Xv, const bf16_t* __restrict__ Wf,
    const float* __restrict__ rowscale, bf16_t* __restrict__ out, int Nrows,
    const int* __restrict__ ei, int E, int FB,
    int* __restrict__ cursor, int* __restrict__ csr_src) {
    __shared__ bf16_t Blds[32768];  // 64 KB: half-K of fragment-major W

    if (blockIdx.x < FB) {
        // ---- fill_csr part (block-uniform branch; no barriers) ----
        int e = blockIdx.x * 512 + threadIdx.x;
        if (e < E) {
            int src = ei[e];
            int dst = ei[E + e];
            int pos = atomicAdd(&cursor[dst], 1);
            csr_src[pos] = src;
        }
        return;
    }

    const int tid = threadIdx.x;
    const int wave = tid >> 6;   // 0..7
    const int lane = tid & 63;
    const int row0 = (blockIdx.x - FB) * GBM;
    const int m = lane & 15;   // A-row / B-col / D-col within 16-tile
    const int kg = lane >> 4;  // k-group 0..3

    const int arow_raw = row0 + wave * 16 + m;
    const int arow = (arow_raw < Nrows) ? arow_raw : 0;  // clamp; stores masked

    f32x4 acc[16];
#pragma unroll
    for (int i = 0; i < 16; ++i) acc[i] = (f32x4){0.f, 0.f, 0.f, 0.f};

#pragma unroll
    for (int c = 0; c < 2; ++c) {
        // ---- pre-issue this chunk's A loads (regs; don't touch LDS) ----
        float4 xa0, xb0, xa1, xb1, xa2, xb2, xa3, xb3;  // INFP32
        bf16x8 ah0, ah1, ah2, ah3;                       // !INFP32
        if (INFP32) {
            const float* xr = (const float*)Xv + (size_t)arow * 256 + c * 128 + kg * 8;
            xa0 = *(const float4*)&xr[0];   xb0 = *(const float4*)&xr[4];
            xa1 = *(const float4*)&xr[32];  xb1 = *(const float4*)&xr[36];
            xa2 = *(const float4*)&xr[64];  xb2 = *(const float4*)&xr[68];
            xa3 = *(const float4*)&xr[96];  xb3 = *(const float4*)&xr[100];
        } else {
            const bf16_t* xr = (const bf16_t*)Xv + (size_t)arow * 256 + c * 128 + kg * 8;
            ah0 = *(const bf16x8*)&xr[0];
            ah1 = *(const bf16x8*)&xr[32];
            ah2 = *(const bf16x8*)&xr[64];
            ah3 = *(const bf16x8*)&xr[96];
        }

        if (c) __syncthreads();  // chunk 0 fully consumed before overwrite

        // ---- stage 64KB W chunk into LDS ----
#if __has_builtin(__builtin_amdgcn_global_load_lds)
        {
            // async direct-to-LDS: wave-uniform LDS base + lane*16 (linear)
            const bf16_t* gsrc = Wf + c * 32768;
            const int wbase = (tid >> 6) * 512;  // wave-uniform elem offset
#pragma unroll
            for (int it = 0; it < 8; ++it) {
                __builtin_amdgcn_global_load_lds(
                    (const __attribute__((address_space(1))) void*)(gsrc + it * 4096 + tid * 8),
                    (__attribute__((address_space(3))) void*)(Blds + it * 4096 + wbase),
                    16, 0, 0);
            }
        }
#else
#pragma unroll
        for (int it = 0; it < 8; ++it)
            *(bf16x8*)&Blds[it * 4096 + tid * 8] =
                *(const bf16x8*)&Wf[c * 32768 + it * 4096 + tid * 8];
#endif
        __syncthreads();

        // ---- 4 K-steps from LDS ----
#pragma unroll
        for (int k0c = 0; k0c < 4; ++k0c) {
            bf16x8 ah;
            if (INFP32) {
                float4 xa = (k0c == 0) ? xa0 : (k0c == 1) ? xa1 : (k0c == 2) ? xa2 : xa3;
                float4 xb = (k0c == 0) ? xb0 : (k0c == 1) ? xb1 : (k0c == 2) ? xb2 : xb3;
                float xf[8] = {xa.x, xa.y, xa.z, xa.w, xb.x, xb.y, xb.z, xb.w};
#pragma unroll
                for (int q = 0; q < 8; ++q) ah[q] = (bf16_t)xf[q];
            } else {
                ah = (k0c == 0) ? ah0 : (k0c == 1) ? ah1 : (k0c == 2) ? ah2 : ah3;
            }
#pragma unroll
            for (int nt = 0; nt < 16; ++nt) {
                bf16x8 bh = *(const bf16x8*)&Blds[(k0c * 16 + nt) * 512 + lane * 8];
                acc[nt] = __builtin_amdgcn_mfma_f32_16x16x32_bf16(ah, bh, acc[nt], 0, 0, 0);
            }
        }
    }

    // ---- epilogue: D col = lane&15, row = kg*4 + reg; bf16 output ----
    const int rbase = row0 + wave * 16 + kg * 4;
#pragma unroll
    for (int j = 0; j < 4; ++j) {
        int r = rbase + j;
        if (r < Nrows) {
            float sc = rowscale[r];
#pragma unroll
            for (int nt = 0; nt < 16; ++nt)
                out[(size_t)r * 256 + nt * 16 + m] = (bf16_t)(acc[nt][j] * sc);
        }
    }
}

// ---------------------------------------------------------------------------
// Aggregation: out[i,:] = relu( inv_d[i] * (hs[i,:] + sum_{src->i} hs[src,:]) + b )
// 2 nodes per wave, 32 lanes x bf16x8 (16B) loads. BW-bound floor confirmed
// (rounds 9-16: dur 77-78us, FETCH ~216MB invariant under 5 variants).
// ---------------------------------------------------------------------------
template <typename OutT>
__global__ __launch_bounds__(256) void gcn_aggregate_kernel(
    const bf16_t* __restrict__ hs, const int* __restrict__ rowptr,
    const int* __restrict__ deg, const int* __restrict__ csr_src,
    const float* __restrict__ inv_d, const float* __restrict__ bias,
    OutT* __restrict__ out, int N) {
    int gwid = (blockIdx.x * blockDim.x + threadIdx.x) >> 6;
    int lane = threadIdx.x & 63;
    int node = gwid * 2 + (lane >> 5);
    int hl = lane & 31;
    if (node >= N) return;
    int base = rowptr[node];
    int len = deg[node];
    int c = hl * 8;

    bf16x8 sv = *(const bf16x8*)&hs[(size_t)node * 256 + c];
    float a0[8], a1[8];
#pragma unroll
    for (int q = 0; q < 8; ++q) { a0[q] = (float)sv[q]; a1[q] = 0.f; }

    int i = 0;
    for (; i + 4 <= len; i += 4) {
        int s0 = csr_src[base + i];
        int s1 = csr_src[base + i + 1];
        int s2 = csr_src[base + i + 2];
        int s3 = csr_src[base + i + 3];
        bf16x8 v0 = *(const bf16x8*)&hs[(size_t)s0 * 256 + c];
        bf16x8 v1 = *(const bf16x8*)&hs[(size_t)s1 * 256 + c];
        bf16x8 v2 = *(const bf16x8*)&hs[(size_t)s2 * 256 + c];
        bf16x8 v3 = *(const bf16x8*)&hs[(size_t)s3 * 256 + c];
#pragma unroll
        for (int q = 0; q < 8; ++q) {
            a0[q] += (float)v0[q] + (float)v2[q];
            a1[q] += (float)v1[q] + (float)v3[q];
        }
    }
    for (; i < len; ++i) {
        int s = csr_src[base + i];
        bf16x8 v = *(const bf16x8*)&hs[(size_t)s * 256 + c];
#pragma unroll
        for (int q = 0; q < 8; ++q) a0[q] += (float)v[q];
    }

    float sc = inv_d[node];
    float4 bbA = *(const float4*)&bias[c];
    float4 bbB = *(const float4*)&bias[c + 4];
    float bb[8] = {bbA.x, bbA.y, bbA.z, bbA.w, bbB.x, bbB.y, bbB.z, bbB.w};
    float o[8];
#pragma unroll
    for (int q = 0; q < 8; ++q)
        o[q] = fmaxf(fmaf(a0[q] + a1[q], sc, bb[q]), 0.f);

    if constexpr (sizeof(OutT) == 2) {
        bf16x8 ov;
#pragma unroll
        for (int q = 0; q < 8; ++q) ov[q] = (bf16_t)o[q];
        *(bf16x8*)&out[(size_t)node * 256 + c] = ov;
    } else {
        float4 oA = {o[0], o[1], o[2], o[3]};
        float4 oB = {o[4], o[5], o[6], o[7]};
        *(float4*)&out[(size_t)node * 256 + c] = oA;
        *(float4*)&out[(size_t)node * 256 + c + 4] = oB;
    }
}

// 4x-parallel pool: grid (G, 4 col-chunks); 256 threads = 64 cols x 4 row-groups.
__global__ __launch_bounds__(256) void pool_mean_kernel(
    const float* __restrict__ emb, const int* __restrict__ gstart,
    float* __restrict__ gemb) {
    __shared__ float red[4][64];
    int g = blockIdx.x;
    int col = blockIdx.y * 64 + (threadIdx.x & 63);
    int rg = threadIdx.x >> 6;  // 0..3
    int s = gstart[g], e = gstart[g + 1];
    float sum = 0.f;
    for (int n = s + rg; n < e; n += 4) sum += emb[(size_t)n * 256 + col];
    red[rg][threadIdx.x & 63] = sum;
    __syncthreads();
    if (rg == 0) {
        int l = threadIdx.x & 63;
        float t = (red[0][l] + red[1][l]) + (red[2][l] + red[3][l]);
        float cnt = fmaxf((float)(e - s), 1.0f);
        gemb[g * 256 + col] = t / cnt;
    }
}

// Fused classifier: block per graph. hcls row in LDS, then logits.
__global__ __launch_bounds__(128) void cls_kernel(
    const float* __restrict__ gemb, const float* __restrict__ Wc1,
    const float* __restrict__ bc1, const float* __restrict__ Wc2,
    const float* __restrict__ bc2, float* __restrict__ logits) {
    __shared__ float hl[128];
    int g = blockIdx.x, j = threadIdx.x;
    float sum = bc1[j];
    for (int k = 0; k < 256; ++k) sum = fmaf(gemb[g * 256 + k], Wc1[k * 128 + j], sum);
    hl[j] = fmaxf(sum, 0.f);
    __syncthreads();
    if (j < 2) {
        float s = bc2[j];
        for (int k = 0; k < 128; ++k) s = fmaf(hl[k], Wc2[k * 2 + j], s);
        logits[g * 2 + j] = s;
    }
}

// ---------------------------------------------------------------------------
extern "C" void kernel_launch(void* const* d_in, const int* in_sizes, int n_in,
                              void* d_out, int out_size, void* d_ws, size_t ws_size,
                              hipStream_t stream) {
    const float* x   = (const float*)d_in[0];
    const int*   ei  = (const int*)d_in[1];
    const int*   batch = (const int*)d_in[2];
    // d_in[3] = num_graphs (device scalar) — known statically: 256
    const float* W1  = (const float*)d_in[4];
    const float* b1  = (const float*)d_in[5];
    const float* W2  = (const float*)d_in[6];
    const float* b2  = (const float*)d_in[7];
    const float* Wc1 = (const float*)d_in[8];
    const float* bc1 = (const float*)d_in[9];
    const float* Wc2 = (const float*)d_in[10];
    const float* bc2 = (const float*)d_in[11];

    const int N = in_sizes[0] / HID;   // 100000
    const int E = in_sizes[1] / 2;     // 800000
    const int G = NGRAPH;              // 256

    float* logits   = (float*)d_out;                  // G*2
    float* node_out = (float*)d_out + (size_t)G * 2;  // N*HID final node_emb

    // workspace layout
    char* wsb = (char*)d_ws;
    size_t off = 0;
    auto alloc = [&](size_t bytes) -> void* {
        void* p = wsb + off;
        off += (bytes + 255) & ~(size_t)255;
        return p;
    };
    bf16_t* hs     = (bf16_t*)alloc((size_t)N * HID * 2);  // 51.2 MB (h@W scaled)
    bf16_t* hb     = (bf16_t*)alloc((size_t)N * HID * 2);  // 51.2 MB (layer-1 h, bf16)
    int*    rowptr = (int*)alloc((size_t)N * 4);
    int*    cursor = (int*)alloc((size_t)N * 4);
    int*    degi   = (int*)alloc((size_t)N * 4);
    int*    csr    = (int*)alloc((size_t)E * 4);
    float*  invd   = (float*)alloc((size_t)N * 4);
    int*    gstart = (int*)alloc((size_t)(G + 1) * 4);
    float*  gemb   = (float*)alloc((size_t)G * HID * 4);
    int*    bsum   = (int*)alloc(256 * 4);
    int*    boff   = (int*)alloc(256 * 4);
    bf16_t* wf1    = (bf16_t*)alloc((size_t)HID * HID * 2);  // 128 KB
    bf16_t* wf2    = (bf16_t*)alloc((size_t)HID * HID * 2);  // 128 KB
    (void)ws_size; (void)n_in; (void)out_size;

    const int NB = (N + SCHUNK - 1) / SCHUNK;  // 196 scan blocks
    const int ZB = (N + 255) / 256;            // zero blocks
    const int CB = (E + 255) / 256;            // count blocks
    const int BB = (N + 1 + 255) / 256;        // bounds blocks

    // ---- CSR build + W prep (fused launches) ----
    prep_kernel<<<ZB + 2 * HID * HID / 256, 256, 0, stream>>>(degi, N, ZB, W1, wf1, W2, wf2);
    count_bounds_kernel<<<CB + BB, 256, 0, stream>>>(ei, E, CB, degi, batch, N, G, gstart);
    scan_pass1_kernel<<<NB, 256, 0, stream>>>(degi, N, bsum);
    scan_pass2_kernel<<<1, 256, 0, stream>>>(bsum, NB, boff);
    scan_pass3_kernel<<<NB, 256, 0, stream>>>(degi, N, boff, rowptr, cursor, invd);

    const int GB = (N + GBM - 1) / GBM;             // 782 GEMM blocks
    const int FB = (E + 511) / 512;                 // 1563 fill blocks
    const int AB = ((N + 1) / 2 * 64 + 255) / 256;  // agg blocks (2 nodes/wave)

    // ---- layer 1: fill_csr fused with gemm1 (independent work, overlapped) ----
    gemm_fill_kernel<1><<<FB + GB, 512, 0, stream>>>(
        x, wf1, invd, hs, N, ei, E, FB, cursor, csr);
    gcn_aggregate_kernel<bf16_t><<<AB, 256, 0, stream>>>(
        hs, rowptr, degi, csr, invd, b1, hb, N);          // h (bf16)

    // ---- layer 2: bf16 h, single product ----
    gemm_fill_kernel<0><<<GB, 512, 0, stream>>>(
        hb, wf2, invd, hs, N, nullptr, 0, 0, nullptr, nullptr);
    gcn_aggregate_kernel<float><<<AB, 256, 0, stream>>>(
        hs, rowptr, degi, csr, invd, b2, node_out, N);    // node_emb (fp32)

    // ---- pooling + classifier ----
    pool_mean_kernel<<<dim3(G, 4), 256, 0, stream>>>(node_out, gstart, gemb);
    cls_kernel<<<G, 128, 0, stream>>>(gemb, Wc1, bc1, Wc2, bc2, logits);
}

// Round 18
// 363.002 us; speedup vs baseline: 1.0242x; 1.0242x over previous
//
#include <hip/hip_runtime.h>
#include <hip/hip_bf16.h>

// Problem constants (from reference): N=100000, F_IN=HID=256, E=800000, G=256
#define HID 256
#define NGRAPH 256

typedef __bf16 bf16_t;
typedef __attribute__((ext_vector_type(8))) __bf16 bf16x8;
typedef __attribute__((ext_vector_type(4))) __bf16 bf16x4;
typedef __attribute__((ext_vector_type(4))) float f32x4;

// ---------------------------------------------------------------------------
// prep: zero degi (blocks [0,ZB)) + W1/W2 -> fragment-major bf16 (rest).
//   Wf[((k0*16 + nt)*64 + kg*16 + m)*8 + j] = bf16( W[k0*32+kg*8+j][nt*16+m] )
// ---------------------------------------------------------------------------
__global__ __launch_bounds__(256) void prep_kernel(
    int* __restrict__ degi, int N, int ZB,
    const float* __restrict__ W1, bf16_t* __restrict__ Wf1,
    const float* __restrict__ W2, bf16_t* __restrict__ Wf2) {
    int b = blockIdx.x;
    if (b < ZB) {
        int i = b * 256 + threadIdx.x;
        if (i < N) degi[i] = 0;
        return;
    }
    int gi = (b - ZB) * 256 + threadIdx.x;  // 0..131071
    const float* W = (gi < 65536) ? W1 : W2;
    bf16_t* Wf = (gi < 65536) ? Wf1 : Wf2;
    int idx = gi & 65535;
    float w = W[idx];
    int k = idx >> 8, n = idx & 255;
    int k0 = k >> 5, kg = (k >> 3) & 3, j = k & 7;
    int nt = n >> 4, m = n & 15;
    Wf[(size_t)(((k0 * 16 + nt) * 64) + kg * 16 + m) * 8 + j] = (bf16_t)w;
}

// ---------------------------------------------------------------------------
// count_deg (blocks [0,CB)) + graph_bounds (rest; batch sorted).
// ---------------------------------------------------------------------------
__global__ void count_bounds_kernel(const int* __restrict__ ei, int E, int CB,
                                    int* __restrict__ deg,
                                    const int* __restrict__ batch, int N, int G,
                                    int* __restrict__ gstart) {
    int b = blockIdx.x;
    if (b < CB) {
        int e = b * 256 + threadIdx.x;
        if (e < E) atomicAdd(&deg[ei[E + e]], 1);
        return;
    }
    int i = (b - CB) * 256 + threadIdx.x;
    if (i > N) return;
    int cur = (i < N) ? batch[i] : G;
    int prev = (i == 0) ? -1 : batch[i - 1];
    for (int g = prev + 1; g <= cur; ++g) gstart[g] = i;
}

#define SCHUNK 512

__global__ __launch_bounds__(256) void scan_pass1_kernel(
    const int* __restrict__ deg, int N, int* __restrict__ bsum) {
    __shared__ int red[256];
    int b = blockIdx.x, t = threadIdx.x;
    int i0 = b * SCHUNK + 2 * t;
    int v = 0;
    if (i0 < N) v += deg[i0];
    if (i0 + 1 < N) v += deg[i0 + 1];
    red[t] = v;
    __syncthreads();
    for (int s = 128; s > 0; s >>= 1) {
        if (t < s) red[t] += red[t + s];
        __syncthreads();
    }
    if (t == 0) bsum[b] = red[0];
}

__global__ __launch_bounds__(256) void scan_pass2_kernel(
    const int* __restrict__ bsum, int NB, int* __restrict__ boff) {
    __shared__ int s[256];
    int t = threadIdx.x;
    int v = (t < NB) ? bsum[t] : 0;
    s[t] = v;
    __syncthreads();
    for (int off = 1; off < 256; off <<= 1) {
        int x = s[t];
        if (t >= off) x += s[t - off];
        __syncthreads();
        s[t] = x;
        __syncthreads();
    }
    if (t < NB) boff[t] = s[t] - v;  // exclusive
}

__global__ __launch_bounds__(256) void scan_pass3_kernel(
    const int* __restrict__ deg, int N, const int* __restrict__ boff,
    int* __restrict__ rowptr, int* __restrict__ cursor, float* __restrict__ invd) {
    __shared__ int s[256];
    int b = blockIdx.x, t = threadIdx.x;
    int i0 = b * SCHUNK + 2 * t;
    int d0 = (i0 < N) ? deg[i0] : 0;
    int d1 = (i0 + 1 < N) ? deg[i0 + 1] : 0;
    int pair = d0 + d1;
    s[t] = pair;
    __syncthreads();
    for (int off = 1; off < 256; off <<= 1) {
        int x = s[t];
        if (t >= off) x += s[t - off];
        __syncthreads();
        s[t] = x;
        __syncthreads();
    }
    int excl = s[t] - pair + boff[b];
    if (i0 < N) {
        rowptr[i0] = excl;
        cursor[i0] = excl;
        invd[i0] = rsqrtf((float)d0 + 1.0f);
    }
    if (i0 + 1 < N) {
        int e1 = excl + d0;
        rowptr[i0 + 1] = e1;
        cursor[i0 + 1] = e1;
        invd[i0 + 1] = rsqrtf((float)d1 + 1.0f);
    }
}

__global__ void fill_csr_kernel(const int* __restrict__ ei, int E,
                                int* __restrict__ cursor, int* __restrict__ csr_src) {
    int e = blockIdx.x * blockDim.x + threadIdx.x;
    if (e >= E) return;
    int src = ei[e];
    int dst = ei[E + e];
    int pos = atomicAdd(&cursor[dst], 1);
    csr_src[pos] = src;
}

// ---------------------------------------------------------------------------
// MFMA GEMM (round-16 form — best measured config, 367.6us total):
// hs[i,:] = bf16( (X[i,:] @ W) * rowscale[i] ). Single product both layers
// (layer-1 x quantized to bf16 in-register). GBM=128, 512-thread blocks,
// B staged in LDS in two 64KB half-K chunks via register staging (round-17's
// async global_load_lds + fill-fusion regressed; block-concat fusion of
// heterogeneous work falsified twice — short uniform blocks win).
// MFMA layout facts (verified m89/m91): D col=lane&15, row=(lane>>4)*4+reg.
// ---------------------------------------------------------------------------
#define GBM 128

template <int INFP32>
__global__ __launch_bounds__(512, 4) void gemm_mfma_kernel(
    const void* __restrict__ Xv, const bf16_t* __restrict__ Wf,
    const float* __restrict__ rowscale, bf16_t* __restrict__ out, int Nrows) {
    __shared__ bf16_t Blds[32768];  // 64 KB: half-K of fragment-major W

    const int tid = threadIdx.x;
    const int wave = tid >> 6;   // 0..7
    const int lane = tid & 63;
    const int row0 = blockIdx.x * GBM;
    const int m = lane & 15;   // A-row / B-col / D-col within 16-tile
    const int kg = lane >> 4;  // k-group 0..3

    const int arow_raw = row0 + wave * 16 + m;
    const int arow = (arow_raw < Nrows) ? arow_raw : 0;  // clamp; stores masked

    f32x4 acc[16];
#pragma unroll
    for (int i = 0; i < 16; ++i) acc[i] = (f32x4){0.f, 0.f, 0.f, 0.f};

#pragma unroll
    for (int c = 0; c < 2; ++c) {
        // ---- pre-issue this chunk's A loads (latency hides under staging) ----
        float4 xa0, xb0, xa1, xb1, xa2, xb2, xa3, xb3;  // INFP32
        bf16x8 ah0, ah1, ah2, ah3;                       // !INFP32
        if (INFP32) {
            const float* xr = (const float*)Xv + (size_t)arow * 256 + c * 128 + kg * 8;
            xa0 = *(const float4*)&xr[0];   xb0 = *(const float4*)&xr[4];
            xa1 = *(const float4*)&xr[32];  xb1 = *(const float4*)&xr[36];
            xa2 = *(const float4*)&xr[64];  xb2 = *(const float4*)&xr[68];
            xa3 = *(const float4*)&xr[96];  xb3 = *(const float4*)&xr[100];
        } else {
            const bf16_t* xr = (const bf16_t*)Xv + (size_t)arow * 256 + c * 128 + kg * 8;
            ah0 = *(const bf16x8*)&xr[0];
            ah1 = *(const bf16x8*)&xr[32];
            ah2 = *(const bf16x8*)&xr[64];
            ah3 = *(const bf16x8*)&xr[96];
        }

        // ---- stage 64KB W chunk into LDS (512 threads x 8 x bf16x8) ----
        if (c) __syncthreads();  // chunk 0 fully consumed before overwrite
#pragma unroll
        for (int it = 0; it < 8; ++it)
            *(bf16x8*)&Blds[it * 4096 + tid * 8] =
                *(const bf16x8*)&Wf[c * 32768 + it * 4096 + tid * 8];
        __syncthreads();

        // ---- 4 K-steps from LDS ----
#pragma unroll
        for (int k0c = 0; k0c < 4; ++k0c) {
            bf16x8 ah;
            if (INFP32) {
                float4 xa = (k0c == 0) ? xa0 : (k0c == 1) ? xa1 : (k0c == 2) ? xa2 : xa3;
                float4 xb = (k0c == 0) ? xb0 : (k0c == 1) ? xb1 : (k0c == 2) ? xb2 : xb3;
                float xf[8] = {xa.x, xa.y, xa.z, xa.w, xb.x, xb.y, xb.z, xb.w};
#pragma unroll
                for (int q = 0; q < 8; ++q) ah[q] = (bf16_t)xf[q];
            } else {
                ah = (k0c == 0) ? ah0 : (k0c == 1) ? ah1 : (k0c == 2) ? ah2 : ah3;
            }
#pragma unroll
            for (int nt = 0; nt < 16; ++nt) {
                bf16x8 bh = *(const bf16x8*)&Blds[(k0c * 16 + nt) * 512 + lane * 8];
                acc[nt] = __builtin_amdgcn_mfma_f32_16x16x32_bf16(ah, bh, acc[nt], 0, 0, 0);
            }
        }
    }

    // ---- epilogue: D col = lane&15, row = kg*4 + reg; bf16 output ----
    const int rbase = row0 + wave * 16 + kg * 4;
#pragma unroll
    for (int j = 0; j < 4; ++j) {
        int r = rbase + j;
        if (r < Nrows) {
            float sc = rowscale[r];
#pragma unroll
            for (int nt = 0; nt < 16; ++nt)
                out[(size_t)r * 256 + nt * 16 + m] = (bf16_t)(acc[nt][j] * sc);
        }
    }
}

// ---------------------------------------------------------------------------
// Aggregation: out[i,:] = relu( inv_d[i] * (hs[i,:] + sum_{src->i} hs[src,:]) + b )
// 2 nodes per wave, 32 lanes x bf16x8 (16B) loads. BW-bound floor confirmed
// (rounds 9-17: dur 77-78us, FETCH ~216MB invariant under 5 variants).
// ---------------------------------------------------------------------------
template <typename OutT>
__global__ __launch_bounds__(256) void gcn_aggregate_kernel(
    const bf16_t* __restrict__ hs, const int* __restrict__ rowptr,
    const int* __restrict__ deg, const int* __restrict__ csr_src,
    const float* __restrict__ inv_d, const float* __restrict__ bias,
    OutT* __restrict__ out, int N) {
    int gwid = (blockIdx.x * blockDim.x + threadIdx.x) >> 6;
    int lane = threadIdx.x & 63;
    int node = gwid * 2 + (lane >> 5);
    int hl = lane & 31;
    if (node >= N) return;
    int base = rowptr[node];
    int len = deg[node];
    int c = hl * 8;

    bf16x8 sv = *(const bf16x8*)&hs[(size_t)node * 256 + c];
    float a0[8], a1[8];
#pragma unroll
    for (int q = 0; q < 8; ++q) { a0[q] = (float)sv[q]; a1[q] = 0.f; }

    int i = 0;
    for (; i + 4 <= len; i += 4) {
        int s0 = csr_src[base + i];
        int s1 = csr_src[base + i + 1];
        int s2 = csr_src[base + i + 2];
        int s3 = csr_src[base + i + 3];
        bf16x8 v0 = *(const bf16x8*)&hs[(size_t)s0 * 256 + c];
        bf16x8 v1 = *(const bf16x8*)&hs[(size_t)s1 * 256 + c];
        bf16x8 v2 = *(const bf16x8*)&hs[(size_t)s2 * 256 + c];
        bf16x8 v3 = *(const bf16x8*)&hs[(size_t)s3 * 256 + c];
#pragma unroll
        for (int q = 0; q < 8; ++q) {
            a0[q] += (float)v0[q] + (float)v2[q];
            a1[q] += (float)v1[q] + (float)v3[q];
        }
    }
    for (; i < len; ++i) {
        int s = csr_src[base + i];
        bf16x8 v = *(const bf16x8*)&hs[(size_t)s * 256 + c];
#pragma unroll
        for (int q = 0; q < 8; ++q) a0[q] += (float)v[q];
    }

    float sc = inv_d[node];
    float4 bbA = *(const float4*)&bias[c];
    float4 bbB = *(const float4*)&bias[c + 4];
    float bb[8] = {bbA.x, bbA.y, bbA.z, bbA.w, bbB.x, bbB.y, bbB.z, bbB.w};
    float o[8];
#pragma unroll
    for (int q = 0; q < 8; ++q)
        o[q] = fmaxf(fmaf(a0[q] + a1[q], sc, bb[q]), 0.f);

    if constexpr (sizeof(OutT) == 2) {
        bf16x8 ov;
#pragma unroll
        for (int q = 0; q < 8; ++q) ov[q] = (bf16_t)o[q];
        *(bf16x8*)&out[(size_t)node * 256 + c] = ov;
    } else {
        float4 oA = {o[0], o[1], o[2], o[3]};
        float4 oB = {o[4], o[5], o[6], o[7]};
        *(float4*)&out[(size_t)node * 256 + c] = oA;
        *(float4*)&out[(size_t)node * 256 + c + 4] = oB;
    }
}

// 4x-parallel pool: grid (G, 4 col-chunks); 256 threads = 64 cols x 4 row-groups.
__global__ __launch_bounds__(256) void pool_mean_kernel(
    const float* __restrict__ emb, const int* __restrict__ gstart,
    float* __restrict__ gemb) {
    __shared__ float red[4][64];
    int g = blockIdx.x;
    int col = blockIdx.y * 64 + (threadIdx.x & 63);
    int rg = threadIdx.x >> 6;  // 0..3
    int s = gstart[g], e = gstart[g + 1];
    float sum = 0.f;
    for (int n = s + rg; n < e; n += 4) sum += emb[(size_t)n * 256 + col];
    red[rg][threadIdx.x & 63] = sum;
    __syncthreads();
    if (rg == 0) {
        int l = threadIdx.x & 63;
        float t = (red[0][l] + red[1][l]) + (red[2][l] + red[3][l]);
        float cnt = fmaxf((float)(e - s), 1.0f);
        gemb[g * 256 + col] = t / cnt;
    }
}

// Fused classifier: block per graph. hcls row in LDS, then logits.
__global__ __launch_bounds__(128) void cls_kernel(
    const float* __restrict__ gemb, const float* __restrict__ Wc1,
    const float* __restrict__ bc1, const float* __restrict__ Wc2,
    const float* __restrict__ bc2, float* __restrict__ logits) {
    __shared__ float hl[128];
    int g = blockIdx.x, j = threadIdx.x;
    float sum = bc1[j];
    for (int k = 0; k < 256; ++k) sum = fmaf(gemb[g * 256 + k], Wc1[k * 128 + j], sum);
    hl[j] = fmaxf(sum, 0.f);
    __syncthreads();
    if (j < 2) {
        float s = bc2[j];
        for (int k = 0; k < 128; ++k) s = fmaf(hl[k], Wc2[k * 2 + j], s);
        logits[g * 2 + j] = s;
    }
}

// ---------------------------------------------------------------------------
extern "C" void kernel_launch(void* const* d_in, const int* in_sizes, int n_in,
                              void* d_out, int out_size, void* d_ws, size_t ws_size,
                              hipStream_t stream) {
    const float* x   = (const float*)d_in[0];
    const int*   ei  = (const int*)d_in[1];
    const int*   batch = (const int*)d_in[2];
    // d_in[3] = num_graphs (device scalar) — known statically: 256
    const float* W1  = (const float*)d_in[4];
    const float* b1  = (const float*)d_in[5];
    const float* W2  = (const float*)d_in[6];
    const float* b2  = (const float*)d_in[7];
    const float* Wc1 = (const float*)d_in[8];
    const float* bc1 = (const float*)d_in[9];
    const float* Wc2 = (const float*)d_in[10];
    const float* bc2 = (const float*)d_in[11];

    const int N = in_sizes[0] / HID;   // 100000
    const int E = in_sizes[1] / 2;     // 800000
    const int G = NGRAPH;              // 256

    float* logits   = (float*)d_out;                  // G*2
    float* node_out = (float*)d_out + (size_t)G * 2;  // N*HID final node_emb

    // workspace layout
    char* wsb = (char*)d_ws;
    size_t off = 0;
    auto alloc = [&](size_t bytes) -> void* {
        void* p = wsb + off;
        off += (bytes + 255) & ~(size_t)255;
        return p;
    };
    bf16_t* hs     = (bf16_t*)alloc((size_t)N * HID * 2);  // 51.2 MB (h@W scaled)
    bf16_t* hb     = (bf16_t*)alloc((size_t)N * HID * 2);  // 51.2 MB (layer-1 h, bf16)
    int*    rowptr = (int*)alloc((size_t)N * 4);
    int*    cursor = (int*)alloc((size_t)N * 4);
    int*    degi   = (int*)alloc((size_t)N * 4);
    int*    csr    = (int*)alloc((size_t)E * 4);
    float*  invd   = (float*)alloc((size_t)N * 4);
    int*    gstart = (int*)alloc((size_t)(G + 1) * 4);
    float*  gemb   = (float*)alloc((size_t)G * HID * 4);
    int*    bsum   = (int*)alloc(256 * 4);
    int*    boff   = (int*)alloc(256 * 4);
    bf16_t* wf1    = (bf16_t*)alloc((size_t)HID * HID * 2);  // 128 KB
    bf16_t* wf2    = (bf16_t*)alloc((size_t)HID * HID * 2);  // 128 KB
    (void)ws_size; (void)n_in; (void)out_size;

    const int NB = (N + SCHUNK - 1) / SCHUNK;  // 196 scan blocks
    const int ZB = (N + 255) / 256;            // zero blocks
    const int CB = (E + 255) / 256;            // count blocks
    const int BB = (N + 1 + 255) / 256;        // bounds blocks

    // ---- CSR build + W prep (fused launches) ----
    prep_kernel<<<ZB + 2 * HID * HID / 256, 256, 0, stream>>>(degi, N, ZB, W1, wf1, W2, wf2);
    count_bounds_kernel<<<CB + BB, 256, 0, stream>>>(ei, E, CB, degi, batch, N, G, gstart);
    scan_pass1_kernel<<<NB, 256, 0, stream>>>(degi, N, bsum);
    scan_pass2_kernel<<<1, 256, 0, stream>>>(bsum, NB, boff);
    scan_pass3_kernel<<<NB, 256, 0, stream>>>(degi, N, boff, rowptr, cursor, invd);
    fill_csr_kernel<<<(E + 255) / 256, 256, 0, stream>>>(ei, E, cursor, csr);

    const int GB = (N + GBM - 1) / GBM;             // 782 GEMM blocks
    const int AB = ((N + 1) / 2 * 64 + 255) / 256;  // agg blocks (2 nodes/wave)

    // ---- layer 1: fp32 x (bf16-quantized in-register), single product ----
    gemm_mfma_kernel<1><<<GB, 512, 0, stream>>>(x, wf1, invd, hs, N);
    gcn_aggregate_kernel<bf16_t><<<AB, 256, 0, stream>>>(
        hs, rowptr, degi, csr, invd, b1, hb, N);          // h (bf16)

    // ---- layer 2: bf16 h, single product ----
    gemm_mfma_kernel<0><<<GB, 512, 0, stream>>>(hb, wf2, invd, hs, N);
    gcn_aggregate_kernel<float><<<AB, 256, 0, stream>>>(
        hs, rowptr, degi, csr, invd, b2, node_out, N);    // node_emb (fp32)

    // ---- pooling + classifier ----
    pool_mean_kernel<<<dim3(G, 4), 256, 0, stream>>>(node_out, gstart, gemb);
    cls_kernel<<<G, 128, 0, stream>>>(gemb, Wc1, bc1, Wc2, bc2, logits);
}